// Round 4
// baseline (6543.041 us; speedup 1.0000x reference)
//
#include <hip/hip_runtime.h>
#include <hip/hip_fp16.h>

// Journal:
// R1: full pipeline, MFMA everywhere -> out0 err 0.59; out1 structurally wrong.
// R2: out1 fixed; post-pool all-f32 -> err bit-identical 0.59375.
// R3: dtype-detector theory -> flag=0 (inputs are f32), no change. WRONG theory.
// R4: REAL BUG FOUND: final log_softmax subtracted m twice (lse already
//     includes +m). out = l - lse, not l - m - lse. Error |m_row| ~= 0.59
//     matches observed exactly. R1-vs-R2 bit-identity = bf16-grid compare +
//     logits agreeing to ~1e-3 across two independent post-pool impls (which
//     cross-validates the whole upstream pipeline).

#define BN 64
#define EVI 5
#define SEQS (BN * EVI)
#define LSEQ 256
#define DIM 768
#define WORDS 32
#define TPW 4
#define NNODE (BN * EVI * WORDS)   // 10240
#define NEDGE (NNODE * 16)         // 163840
#define RREL 4
#define DOUT 768
#define LH 1024
#define NCLS 3
#define KBIG (5 * DIM)             // 3840
#define KATT (DIM + 2 * DOUT)      // 2304

typedef float f32x4 __attribute__((ext_vector_type(4)));
typedef __bf16 bf16x8 __attribute__((ext_vector_type(8)));

__device__ inline unsigned short f2bf(float f) {
    union { float f; unsigned int u; } v; v.f = f;
    unsigned int u = v.u;
    unsigned int lsb = (u >> 16) & 1u;
    u += 0x7fffu + lsb;
    return (unsigned short)(u >> 16);
}
__device__ inline float bf2f(unsigned short h) {
    union { float f; unsigned int u; } v; v.u = ((unsigned int)h) << 16; return v.f;
}

// flag: 0 = f32, 1 = fp16, 2 = bf16 storage of "float32" inputs
__device__ inline float ldin(const void* p, long i, int f) {
    if (f == 1) return __half2float(((const __half*)p)[i]);
    if (f == 2) return bf2f(((const unsigned short*)p)[i]);
    return ((const float*)p)[i];
}

// ---------------- dtype detector (no-op safety; R3 showed flag=0) ----------
__global__ void detect_kernel(const void* w, int* flag) {
    if (threadIdx.x != 0 || blockIdx.x != 0) return;
    const unsigned int* u32 = (const unsigned int*)w;
    const unsigned short* u16 = (const unsigned short*)w;
    int tiny = 0;
    for (int i = 0; i < 2048; i++) {
        unsigned int b = u32[i];
        float f; __builtin_memcpy(&f, &b, 4);
        float a = fabsf(f);
        if (!(a > 1e-10f)) tiny++;
    }
    if (tiny > 1024) { *flag = 1; return; }
    int band = 0;
    for (int i = 0; i < 4096; i++) {
        unsigned short h = u16[i];
        int e8 = (h >> 7) & 0xFF;
        if (h == 0 || (e8 >= 0x66 && e8 <= 0x86)) band++;
    }
    *flag = (band > 3900) ? 2 : 0;
}

// ---------------- canonicalize a float input to f32 ----------------
__global__ void convert_kernel(const void* __restrict__ src, float* __restrict__ dst,
                               long n, const int* __restrict__ flag)
{
    int f = *flag;
    long stride = (long)gridDim.x * 256;
    for (long i = (long)blockIdx.x * 256 + threadIdx.x; i < n; i += stride)
        dst[i] = ldin(src, i, f);
}

// ---------------- token gather + mean over TPW ----------------
__global__ __launch_bounds__(256) void gather_mean_kernel(
    const void* __restrict__ tok, const int* __restrict__ widx,
    unsigned short* __restrict__ xb, const int* __restrict__ flag)
{
    int f = *flag;
    int n = blockIdx.x;
    long i0 = widx[n * 4 + 0], i1 = widx[n * 4 + 1];
    long i2 = widx[n * 4 + 2], i3 = widx[n * 4 + 3];
    for (int c = threadIdx.x; c < DIM; c += 256) {
        float s = ldin(tok, i0 * DIM + c, f) + ldin(tok, i1 * DIM + c, f)
                + ldin(tok, i2 * DIM + c, f) + ldin(tok, i3 * DIM + c, f);
        xb[(long)n * DIM + c] = f2bf(s * 0.25f);
    }
}

// ---------------- edge prep ----------------
__global__ void count_kernel(const int* __restrict__ ei, const int* __restrict__ et,
                             int* __restrict__ cnt)
{
    int e = blockIdx.x * 256 + threadIdx.x;
    if (e >= NEDGE) return;
    int dst = ei[NEDGE + e];
    int r = et[e];
    atomicAdd(&cnt[dst * RREL + r], 1);
}

__global__ __launch_bounds__(1024) void scan_kernel(const int* __restrict__ cnt,
                                                    int* __restrict__ offs, int n)
{
    __shared__ int buf[1024];
    __shared__ int carry;
    int tid = threadIdx.x;
    if (tid == 0) { carry = 0; offs[0] = 0; }
    __syncthreads();
    for (int base = 0; base < n; base += 1024) {
        int v = (base + tid < n) ? cnt[base + tid] : 0;
        buf[tid] = v;
        __syncthreads();
        for (int o = 1; o < 1024; o <<= 1) {
            int t = (tid >= o) ? buf[tid - o] : 0;
            __syncthreads();
            buf[tid] += t;
            __syncthreads();
        }
        if (base + tid < n) offs[base + tid + 1] = carry + buf[tid];
        __syncthreads();
        if (tid == 0) carry += buf[1023];
        __syncthreads();
    }
}

__global__ void fill_kernel(const int* __restrict__ ei, const int* __restrict__ et,
                            const int* __restrict__ offs, int* __restrict__ cursor,
                            int* __restrict__ sorted)
{
    int e = blockIdx.x * 256 + threadIdx.x;
    if (e >= NEDGE) return;
    int src = ei[e];
    int dst = ei[NEDGE + e];
    int r = et[e];
    int seg = dst * RREL + r;
    int pos = offs[seg] + atomicAdd(&cursor[seg], 1);
    sorted[pos] = src;
}

// ---------------- segment aggregation (per node) ----------------
__global__ __launch_bounds__(256) void aggregate_kernel(
    const unsigned short* __restrict__ xsrc, long xstride,
    const int* __restrict__ offs, const int* __restrict__ sorted,
    unsigned short* __restrict__ A, int write_root)
{
    int n = blockIdx.x;
    long base = (long)n * KBIG;
    for (int r = 0; r < RREL; r++) {
        int s0 = offs[n * RREL + r], s1 = offs[n * RREL + r + 1];
        float inv = 1.0f / (float)max(s1 - s0, 1);
        for (int c = threadIdx.x; c < DIM; c += 256) {
            float acc = 0.0f;
            for (int i = s0; i < s1; i++) {
                long s = sorted[i];
                acc += bf2f(xsrc[s * xstride + c]);
            }
            A[base + r * DIM + c] = f2bf(acc * inv);
        }
    }
    if (write_root) {
        for (int c = threadIdx.x; c < DIM; c += 256)
            A[base + 4 * DIM + c] = xsrc[(long)n * xstride + c];
    }
}

// ---------------- transpose + cast f32 -> bf16 ----------------
__global__ __launch_bounds__(256) void transpose_cast_kernel(
    const float* __restrict__ in, int Ncols,
    unsigned short* __restrict__ out, int outStride, int colOff)
{
    __shared__ float t[32][33];
    int kt = blockIdx.x * 32, nt = blockIdx.y * 32;
    int lx = threadIdx.x & 31, ly = threadIdx.x >> 5;
    for (int i = 0; i < 4; i++)
        t[ly + i * 8][lx] = in[(long)(kt + ly + i * 8) * Ncols + nt + lx];
    __syncthreads();
    for (int i = 0; i < 4; i++)
        out[(long)(nt + ly + i * 8) * outStride + colOff + kt + lx] = f2bf(t[lx][ly + i * 8]);
}

// ---------------- MFMA GEMM: C = A (M,K) @ Bt^T, bf16 in, f32 acc --------
__global__ __launch_bounds__(256) void gemm_bt_kernel(
    const unsigned short* __restrict__ A, const unsigned short* __restrict__ Bt,
    int K, const float* __restrict__ bias, int relu,
    float* __restrict__ outF, long strideF,
    unsigned short* __restrict__ outB, long strideB)
{
    __shared__ __align__(16) unsigned short As[128 * 32];
    __shared__ __align__(16) unsigned short Bs[128 * 32];
    const int tid = threadIdx.x;
    const int lane = tid & 63, wv = tid >> 6;
    const int wr = wv >> 1, wc = wv & 1;
    const int lr = lane & 15, q = lane >> 4;
    const long m0 = (long)blockIdx.x * 128, n0 = (long)blockIdx.y * 128;

    f32x4 acc[4][4] = {};

    for (int kt = 0; kt < K; kt += 32) {
#pragma unroll
        for (int i = 0; i < 2; i++) {
            int chunk = i * 256 + tid;
            int row = chunk >> 2, kc = (chunk & 3) * 8;
            const unsigned short* ga = A + (m0 + row) * K + kt + kc;
            const unsigned short* gb = Bt + (n0 + row) * K + kt + kc;
            int ldsbase = (i * 256 + wv * 64) * 8;
            __builtin_amdgcn_global_load_lds(
                (const __attribute__((address_space(1))) void*)ga,
                (__attribute__((address_space(3))) void*)&As[ldsbase], 16, 0, 0);
            __builtin_amdgcn_global_load_lds(
                (const __attribute__((address_space(1))) void*)gb,
                (__attribute__((address_space(3))) void*)&Bs[ldsbase], 16, 0, 0);
        }
        __syncthreads();
        bf16x8 af[4], bfr[4];
#pragma unroll
        for (int i = 0; i < 4; i++)
            af[i] = *(const bf16x8*)&As[(wr * 64 + i * 16 + lr) * 32 + q * 8];
#pragma unroll
        for (int j = 0; j < 4; j++)
            bfr[j] = *(const bf16x8*)&Bs[(wc * 64 + j * 16 + lr) * 32 + q * 8];
#pragma unroll
        for (int i = 0; i < 4; i++)
#pragma unroll
            for (int j = 0; j < 4; j++)
                acc[i][j] = __builtin_amdgcn_mfma_f32_16x16x32_bf16(af[i], bfr[j], acc[i][j], 0, 0, 0);
        __syncthreads();
    }

#pragma unroll
    for (int i = 0; i < 4; i++) {
#pragma unroll
        for (int j = 0; j < 4; j++) {
            long col = n0 + wc * 64 + j * 16 + lr;
            float bv = bias ? bias[col] : 0.0f;
#pragma unroll
            for (int r = 0; r < 4; r++) {
                long row = m0 + wr * 64 + i * 16 + q * 4 + r;
                float v = acc[i][j][r] + bv;
                if (relu) v = fmaxf(v, 0.0f);
                if (outF) outF[row * strideF + col] = v;
                if (outB) outB[row * strideB + col] = f2bf(v);
            }
        }
    }
}

// ---------------- pooling (mean/max over words) + cc, f32 ----------------
__global__ __launch_bounds__(256) void pool_cc_kernel(
    const float* __restrict__ C2, const void* __restrict__ tok,
    const int* __restrict__ csi, float* __restrict__ A3f,
    const int* __restrict__ flag)
{
    int f = *flag;
    int s = blockIdx.x;
    int b = s / EVI;
    long seq = csi[b];
    for (int c = threadIdx.x; c < DIM; c += 256) {
        float mx = -1e30f, sm = 0.0f;
        const float* col = C2 + (long)s * WORDS * DOUT + c;
        for (int w = 0; w < WORDS; w++) {
            float v = col[(long)w * DOUT];
            sm += v;
            mx = fmaxf(mx, v);
        }
        A3f[(long)s * KATT + c] = ldin(tok, seq * LSEQ * DIM + c, f);
        A3f[(long)s * KATT + DIM + c] = sm * (1.0f / WORDS);
        A3f[(long)s * KATT + DIM + DOUT + c] = mx;
    }
}

// ---------------- simple f32 GEMM ----------------
__global__ __launch_bounds__(256) void sgemm_simple_kernel(
    const float* __restrict__ A, const float* __restrict__ W,
    const float* __restrict__ bias, float* __restrict__ C,
    int K, int Nout, int relu)
{
    int i = blockIdx.x;
    const float* arow = A + (long)i * K;
    for (int j = threadIdx.x; j < Nout; j += 256) {
        float s = bias ? bias[j] : 0.0f;
        for (int k = 0; k < K; k++) s += arow[k] * W[(long)k * Nout + j];
        C[(long)i * Nout + j] = relu ? fmaxf(s, 0.0f) : s;
    }
}

// ---------------- p = h @ att_w1 ----------------
__global__ __launch_bounds__(256) void pdot_kernel(
    const float* __restrict__ h, const float* __restrict__ w1, float* __restrict__ p)
{
    int i = blockIdx.x;
    float s = 0.0f;
    for (int k = threadIdx.x; k < DOUT; k += 256) s += h[(long)i * DOUT + k] * w1[k];
    __shared__ float red[256];
    red[threadIdx.x] = s;
    __syncthreads();
    for (int o = 128; o > 0; o >>= 1) {
        if (threadIdx.x < o) red[threadIdx.x] += red[threadIdx.x + o];
        __syncthreads();
    }
    if (threadIdx.x == 0) p[i] = red[0];
}

// ---------------- attention output: sigmoid(p[i]) for all 320 rows ----------
__global__ void att_out_kernel(const float* __restrict__ p, float* __restrict__ out)
{
    int i = blockIdx.x * 256 + threadIdx.x;
    if (i < SEQS) out[BN * NCLS + i] = 1.0f / (1.0f + __expf(-p[i]));
}

// ---------------- softmax over EVI + weighted ev + build A4 (f32) ----------
__global__ __launch_bounds__(256) void softgraph_kernel(
    const float* __restrict__ p, const float* __restrict__ A3f,
    const float* __restrict__ ccls, float* __restrict__ A4f)
{
    int b = blockIdx.x;
    __shared__ float a[EVI];
    if (threadIdx.x == 0) {
        float m = -1e30f;
        for (int e = 0; e < EVI; e++) m = fmaxf(m, p[b * EVI + e]);
        float s = 0.0f, ex[EVI];
        for (int e = 0; e < EVI; e++) { ex[e] = __expf(p[b * EVI + e] - m); s += ex[e]; }
        for (int e = 0; e < EVI; e++) a[e] = ex[e] / s;
    }
    __syncthreads();
    for (int d = threadIdx.x; d < 2 * DOUT; d += 256) {
        float g = 0.0f;
        for (int e = 0; e < EVI; e++)
            g += a[e] * A3f[(long)(b * EVI + e) * KATT + DIM + d];
        A4f[(long)b * KATT + d] = g;
    }
    for (int c = threadIdx.x; c < DIM; c += 256)
        A4f[(long)b * KATT + 2 * DOUT + c] = ccls[(long)b * DIM + c];
}

// ---------------- final: lin2 + log_softmax ----------------
__global__ __launch_bounds__(256) void final_kernel(
    const float* __restrict__ C4, const float* __restrict__ w2,
    const float* __restrict__ bb, float* __restrict__ out)
{
    int b = blockIdx.x;
    float s0 = 0.0f, s1 = 0.0f, s2 = 0.0f;
    for (int k = threadIdx.x; k < LH; k += 256) {
        float h = C4[(long)b * LH + k];
        s0 += h * w2[k * NCLS + 0];
        s1 += h * w2[k * NCLS + 1];
        s2 += h * w2[k * NCLS + 2];
    }
    __shared__ float r0[256], r1[256], r2[256];
    int t = threadIdx.x;
    r0[t] = s0; r1[t] = s1; r2[t] = s2;
    __syncthreads();
    for (int o = 128; o > 0; o >>= 1) {
        if (t < o) { r0[t] += r0[t + o]; r1[t] += r1[t + o]; r2[t] += r2[t + o]; }
        __syncthreads();
    }
    if (t == 0) {
        float l0 = r0[0] + bb[0], l1 = r1[0] + bb[1], l2 = r2[0] + bb[2];
        float m = fmaxf(l0, fmaxf(l1, l2));
        // log_softmax_i = l_i - lse;  lse = m + log(sum exp(l-m)).
        // R1-R3 BUG was an extra "- m" here.
        float lse = logf(__expf(l0 - m) + __expf(l1 - m) + __expf(l2 - m)) + m;
        out[b * NCLS + 0] = l0 - lse;
        out[b * NCLS + 1] = l1 - lse;
        out[b * NCLS + 2] = l2 - lse;
    }
}

extern "C" void kernel_launch(void* const* d_in, const int* in_sizes, int n_in,
                              void* d_out, int out_size, void* d_ws, size_t ws_size,
                              hipStream_t stream)
{
    const void* tok      = d_in[0];
    const void* ccls_r   = d_in[1];
    const void* W_rel1_r = d_in[2];
    const void* W_root1_r= d_in[3];
    const void* b1_r     = d_in[4];
    const void* W_rel2_r = d_in[5];
    const void* W_root2_r= d_in[6];
    const void* b2_r     = d_in[7];
    const void* att_w0_r = d_in[8];
    const void* att_w1_r = d_in[9];
    const void* lin1_w_r = d_in[10];
    const void* lin1_b_r = d_in[11];
    const void* lin2_w_r = d_in[12];
    const void* lin2_b_r = d_in[13];
    const int* widx      = (const int*)d_in[14];
    const int* ei        = (const int*)d_in[15];
    const int* et        = (const int*)d_in[16];
    const int* csi       = (const int*)d_in[17];
    float* out           = (float*)d_out;

    char* ws = (char*)d_ws;
    size_t off = 0;
    auto alloc = [&](size_t bytes) { size_t o = off; off = (off + bytes + 255) & ~(size_t)255; return o; };

    int* flag   = (int*)(ws + alloc(256));
    float* cclsF   = (float*)(ws + alloc((size_t)BN * DIM * 4));
    float* Wrel1F  = (float*)(ws + alloc((size_t)RREL * DIM * DIM * 4));
    float* Wroot1F = (float*)(ws + alloc((size_t)DIM * DIM * 4));
    float* b1F     = (float*)(ws + alloc((size_t)DIM * 4));
    float* Wrel2F  = (float*)(ws + alloc((size_t)RREL * DIM * DOUT * 4));
    float* Wroot2F = (float*)(ws + alloc((size_t)DIM * DOUT * 4));
    float* b2F     = (float*)(ws + alloc((size_t)DOUT * 4));
    float* aw0F    = (float*)(ws + alloc((size_t)KATT * DOUT * 4));
    float* aw1F    = (float*)(ws + alloc((size_t)DOUT * 4));
    float* l1wF    = (float*)(ws + alloc((size_t)KATT * LH * 4));
    float* l1bF    = (float*)(ws + alloc((size_t)LH * 4));
    float* l2wF    = (float*)(ws + alloc((size_t)LH * NCLS * 4));
    float* l2bF    = (float*)(ws + alloc((size_t)NCLS * 4));
    unsigned short* xb  = (unsigned short*)(ws + alloc((size_t)NNODE * DIM * 2));
    unsigned short* A1  = (unsigned short*)(ws + alloc((size_t)NNODE * KBIG * 2));
    unsigned short* X1  = (unsigned short*)(ws + alloc((size_t)NNODE * DOUT * 2));
    unsigned short* Wt1 = (unsigned short*)(ws + alloc((size_t)DIM * KBIG * 2));
    unsigned short* Wt2 = (unsigned short*)(ws + alloc((size_t)DIM * KBIG * 2));
    float* C2           = (float*)(ws + alloc((size_t)NNODE * DOUT * 4));
    float* A3f          = (float*)(ws + alloc((size_t)SEQS * KATT * 4));
    float* C3           = (float*)(ws + alloc((size_t)SEQS * DOUT * 4));
    float* pbuf         = (float*)(ws + alloc((size_t)SEQS * 4));
    float* A4f          = (float*)(ws + alloc((size_t)BN * KATT * 4));
    float* C4           = (float*)(ws + alloc((size_t)BN * LH * 4));
    int* cnt            = (int*)(ws + alloc((size_t)2 * NNODE * RREL * 4));
    int* cursor         = cnt + NNODE * RREL;
    int* offs           = (int*)(ws + alloc((size_t)(NNODE * RREL + 1) * 4));
    int* sorted         = (int*)(ws + alloc((size_t)NEDGE * 4));
    (void)ws_size; (void)in_sizes; (void)n_in; (void)out_size;

    // dtype detect + canonicalize (flag=0 path verified by R3)
    detect_kernel<<<1, 64, 0, stream>>>(W_rel1_r, flag);
    auto conv = [&](const void* src, float* dst, long n) {
        int grid = (int)min((n + 255) / 256, (long)2048);
        convert_kernel<<<grid, 256, 0, stream>>>(src, dst, n, flag);
    };
    conv(ccls_r,   cclsF,   (long)BN * DIM);
    conv(W_rel1_r, Wrel1F,  (long)RREL * DIM * DIM);
    conv(W_root1_r,Wroot1F, (long)DIM * DIM);
    conv(b1_r,     b1F,     DIM);
    conv(W_rel2_r, Wrel2F,  (long)RREL * DIM * DOUT);
    conv(W_root2_r,Wroot2F, (long)DIM * DOUT);
    conv(b2_r,     b2F,     DOUT);
    conv(att_w0_r, aw0F,    (long)KATT * DOUT);
    conv(att_w1_r, aw1F,    DOUT);
    conv(lin1_w_r, l1wF,    (long)KATT * LH);
    conv(lin1_b_r, l1bF,    LH);
    conv(lin2_w_r, l2wF,    (long)LH * NCLS);
    conv(lin2_b_r, l2bF,    NCLS);

    // edge prep
    hipMemsetAsync(cnt, 0, (size_t)2 * NNODE * RREL * 4, stream);
    count_kernel<<<NEDGE / 256, 256, 0, stream>>>(ei, et, cnt);
    scan_kernel<<<1, 1024, 0, stream>>>(cnt, offs, NNODE * RREL);
    fill_kernel<<<NEDGE / 256, 256, 0, stream>>>(ei, et, offs, cursor, sorted);

    // token gather
    gather_mean_kernel<<<NNODE, 256, 0, stream>>>(tok, widx, xb, flag);

    // RGCN weight transposes (f32 -> bf16, B^T layout)
    transpose_cast_kernel<<<dim3(96, 24), 256, 0, stream>>>(Wrel1F, DIM, Wt1, KBIG, 0);
    transpose_cast_kernel<<<dim3(24, 24), 256, 0, stream>>>(Wroot1F, DIM, Wt1, KBIG, 4 * DIM);
    transpose_cast_kernel<<<dim3(96, 24), 256, 0, stream>>>(Wrel2F, DOUT, Wt2, KBIG, 0);
    transpose_cast_kernel<<<dim3(24, 24), 256, 0, stream>>>(Wroot2F, DOUT, Wt2, KBIG, 4 * DIM);

    // layer 1: A1 = [agg_r(xb) | xb];  X1 = relu(A1 @ W1)
    aggregate_kernel<<<NNODE, 256, 0, stream>>>(xb, DIM, offs, sorted, A1, 1);
    gemm_bt_kernel<<<dim3(NNODE / 128, DIM / 128), 256, 0, stream>>>(
        A1, Wt1, KBIG, b1F, 1, nullptr, 0, X1, DOUT);

    // layer 2: A1 = [agg_r(X1) | X1];  C2 = relu(A1 @ W2)  (f32)
    aggregate_kernel<<<NNODE, 256, 0, stream>>>(X1, DOUT, offs, sorted, A1, 1);
    gemm_bt_kernel<<<dim3(NNODE / 128, DOUT / 128), 256, 0, stream>>>(
        A1, Wt2, KBIG, b2F, 1, C2, DOUT, nullptr, 0);

    // pooling + attention MLP (f32)
    pool_cc_kernel<<<SEQS, 256, 0, stream>>>(C2, tok, csi, A3f, flag);
    sgemm_simple_kernel<<<SEQS, 256, 0, stream>>>(A3f, aw0F, nullptr, C3, KATT, DOUT, 1);
    pdot_kernel<<<SEQS, 256, 0, stream>>>(C3, aw1F, pbuf);
    att_out_kernel<<<(SEQS + 255) / 256, 256, 0, stream>>>(pbuf, out);
    softgraph_kernel<<<BN, 256, 0, stream>>>(pbuf, A3f, cclsF, A4f);

    // classifier head (f32)
    sgemm_simple_kernel<<<BN, 256, 0, stream>>>(A4f, l1wF, l1bF, C4, KATT, LH, 1);
    final_kernel<<<BN, 256, 0, stream>>>(C4, l2wF, l2bF, out);
}

// Round 5
// 1233.376 us; speedup vs baseline: 5.3050x; 5.3050x over previous
//
#include <hip/hip_runtime.h>
#include <hip/hip_fp16.h>

// Journal:
// R1: full pipeline, MFMA everywhere -> out0 err 0.59; out1 structurally wrong.
// R2: out1 fixed; post-pool all-f32 -> err bit-identical 0.59375.
// R3: dtype-detector theory -> flag=0 (f32 inputs), no change. Wrong theory.
// R4: REAL BUG: log_softmax subtracted m twice. PASSED, absmax 0.0078,
//     dur 6543us. Profile: sgemm_simple 2x3030us (VALUBusy 0.25%, occ 3%) =
//     latency-bound serial-K naive GEMM.
// R5: att-MLP + lin1 back on MFMA gemm_bt (R1 structure): Wt3/Wt4 bf16 B^T,
//     A3 bf16 384xKATT (320 used), A4 bf16 128xKATT (64 used). evF stays f32
//     for the softmax-weighted graph accumulation. Predict 6543 -> ~550us.

#define BN 64
#define EVI 5
#define SEQS (BN * EVI)
#define LSEQ 256
#define DIM 768
#define WORDS 32
#define TPW 4
#define NNODE (BN * EVI * WORDS)   // 10240
#define NEDGE (NNODE * 16)         // 163840
#define RREL 4
#define DOUT 768
#define LH 1024
#define NCLS 3
#define KBIG (5 * DIM)             // 3840
#define KATT (DIM + 2 * DOUT)      // 2304

typedef float f32x4 __attribute__((ext_vector_type(4)));
typedef __bf16 bf16x8 __attribute__((ext_vector_type(8)));

__device__ inline unsigned short f2bf(float f) {
    union { float f; unsigned int u; } v; v.f = f;
    unsigned int u = v.u;
    unsigned int lsb = (u >> 16) & 1u;
    u += 0x7fffu + lsb;
    return (unsigned short)(u >> 16);
}
__device__ inline float bf2f(unsigned short h) {
    union { float f; unsigned int u; } v; v.u = ((unsigned int)h) << 16; return v.f;
}

// flag: 0 = f32, 1 = fp16, 2 = bf16 storage of "float32" inputs
__device__ inline float ldin(const void* p, long i, int f) {
    if (f == 1) return __half2float(((const __half*)p)[i]);
    if (f == 2) return bf2f(((const unsigned short*)p)[i]);
    return ((const float*)p)[i];
}

// ---------------- dtype detector (no-op safety; R3 showed flag=0) ----------
__global__ void detect_kernel(const void* w, int* flag) {
    if (threadIdx.x != 0 || blockIdx.x != 0) return;
    const unsigned int* u32 = (const unsigned int*)w;
    const unsigned short* u16 = (const unsigned short*)w;
    int tiny = 0;
    for (int i = 0; i < 2048; i++) {
        unsigned int b = u32[i];
        float f; __builtin_memcpy(&f, &b, 4);
        float a = fabsf(f);
        if (!(a > 1e-10f)) tiny++;
    }
    if (tiny > 1024) { *flag = 1; return; }
    int band = 0;
    for (int i = 0; i < 4096; i++) {
        unsigned short h = u16[i];
        int e8 = (h >> 7) & 0xFF;
        if (h == 0 || (e8 >= 0x66 && e8 <= 0x86)) band++;
    }
    *flag = (band > 3900) ? 2 : 0;
}

// ---------------- canonicalize a float input to f32 ----------------
__global__ void convert_kernel(const void* __restrict__ src, float* __restrict__ dst,
                               long n, const int* __restrict__ flag)
{
    int f = *flag;
    long stride = (long)gridDim.x * 256;
    for (long i = (long)blockIdx.x * 256 + threadIdx.x; i < n; i += stride)
        dst[i] = ldin(src, i, f);
}

// ---------------- token gather + mean over TPW ----------------
__global__ __launch_bounds__(256) void gather_mean_kernel(
    const void* __restrict__ tok, const int* __restrict__ widx,
    unsigned short* __restrict__ xb, const int* __restrict__ flag)
{
    int f = *flag;
    int n = blockIdx.x;
    long i0 = widx[n * 4 + 0], i1 = widx[n * 4 + 1];
    long i2 = widx[n * 4 + 2], i3 = widx[n * 4 + 3];
    for (int c = threadIdx.x; c < DIM; c += 256) {
        float s = ldin(tok, i0 * DIM + c, f) + ldin(tok, i1 * DIM + c, f)
                + ldin(tok, i2 * DIM + c, f) + ldin(tok, i3 * DIM + c, f);
        xb[(long)n * DIM + c] = f2bf(s * 0.25f);
    }
}

// ---------------- edge prep ----------------
__global__ void count_kernel(const int* __restrict__ ei, const int* __restrict__ et,
                             int* __restrict__ cnt)
{
    int e = blockIdx.x * 256 + threadIdx.x;
    if (e >= NEDGE) return;
    int dst = ei[NEDGE + e];
    int r = et[e];
    atomicAdd(&cnt[dst * RREL + r], 1);
}

__global__ __launch_bounds__(1024) void scan_kernel(const int* __restrict__ cnt,
                                                    int* __restrict__ offs, int n)
{
    __shared__ int buf[1024];
    __shared__ int carry;
    int tid = threadIdx.x;
    if (tid == 0) { carry = 0; offs[0] = 0; }
    __syncthreads();
    for (int base = 0; base < n; base += 1024) {
        int v = (base + tid < n) ? cnt[base + tid] : 0;
        buf[tid] = v;
        __syncthreads();
        for (int o = 1; o < 1024; o <<= 1) {
            int t = (tid >= o) ? buf[tid - o] : 0;
            __syncthreads();
            buf[tid] += t;
            __syncthreads();
        }
        if (base + tid < n) offs[base + tid + 1] = carry + buf[tid];
        __syncthreads();
        if (tid == 0) carry += buf[1023];
        __syncthreads();
    }
}

__global__ void fill_kernel(const int* __restrict__ ei, const int* __restrict__ et,
                            const int* __restrict__ offs, int* __restrict__ cursor,
                            int* __restrict__ sorted)
{
    int e = blockIdx.x * 256 + threadIdx.x;
    if (e >= NEDGE) return;
    int src = ei[e];
    int dst = ei[NEDGE + e];
    int r = et[e];
    int seg = dst * RREL + r;
    int pos = offs[seg] + atomicAdd(&cursor[seg], 1);
    sorted[pos] = src;
}

// ---------------- segment aggregation (per node) ----------------
__global__ __launch_bounds__(256) void aggregate_kernel(
    const unsigned short* __restrict__ xsrc, long xstride,
    const int* __restrict__ offs, const int* __restrict__ sorted,
    unsigned short* __restrict__ A, int write_root)
{
    int n = blockIdx.x;
    long base = (long)n * KBIG;
    for (int r = 0; r < RREL; r++) {
        int s0 = offs[n * RREL + r], s1 = offs[n * RREL + r + 1];
        float inv = 1.0f / (float)max(s1 - s0, 1);
        for (int c = threadIdx.x; c < DIM; c += 256) {
            float acc = 0.0f;
            for (int i = s0; i < s1; i++) {
                long s = sorted[i];
                acc += bf2f(xsrc[s * xstride + c]);
            }
            A[base + r * DIM + c] = f2bf(acc * inv);
        }
    }
    if (write_root) {
        for (int c = threadIdx.x; c < DIM; c += 256)
            A[base + 4 * DIM + c] = xsrc[(long)n * xstride + c];
    }
}

// ---------------- transpose + cast f32 -> bf16 ----------------
__global__ __launch_bounds__(256) void transpose_cast_kernel(
    const float* __restrict__ in, int Ncols,
    unsigned short* __restrict__ out, int outStride, int colOff)
{
    __shared__ float t[32][33];
    int kt = blockIdx.x * 32, nt = blockIdx.y * 32;
    int lx = threadIdx.x & 31, ly = threadIdx.x >> 5;
    for (int i = 0; i < 4; i++)
        t[ly + i * 8][lx] = in[(long)(kt + ly + i * 8) * Ncols + nt + lx];
    __syncthreads();
    for (int i = 0; i < 4; i++)
        out[(long)(nt + ly + i * 8) * outStride + colOff + kt + lx] = f2bf(t[lx][ly + i * 8]);
}

// ---------------- MFMA GEMM: C = A (M,K) @ Bt^T, bf16 in, f32 acc --------
__global__ __launch_bounds__(256) void gemm_bt_kernel(
    const unsigned short* __restrict__ A, const unsigned short* __restrict__ Bt,
    int K, const float* __restrict__ bias, int relu,
    float* __restrict__ outF, long strideF,
    unsigned short* __restrict__ outB, long strideB)
{
    __shared__ __align__(16) unsigned short As[128 * 32];
    __shared__ __align__(16) unsigned short Bs[128 * 32];
    const int tid = threadIdx.x;
    const int lane = tid & 63, wv = tid >> 6;
    const int wr = wv >> 1, wc = wv & 1;
    const int lr = lane & 15, q = lane >> 4;
    const long m0 = (long)blockIdx.x * 128, n0 = (long)blockIdx.y * 128;

    f32x4 acc[4][4] = {};

    for (int kt = 0; kt < K; kt += 32) {
#pragma unroll
        for (int i = 0; i < 2; i++) {
            int chunk = i * 256 + tid;
            int row = chunk >> 2, kc = (chunk & 3) * 8;
            const unsigned short* ga = A + (m0 + row) * K + kt + kc;
            const unsigned short* gb = Bt + (n0 + row) * K + kt + kc;
            int ldsbase = (i * 256 + wv * 64) * 8;
            __builtin_amdgcn_global_load_lds(
                (const __attribute__((address_space(1))) void*)ga,
                (__attribute__((address_space(3))) void*)&As[ldsbase], 16, 0, 0);
            __builtin_amdgcn_global_load_lds(
                (const __attribute__((address_space(1))) void*)gb,
                (__attribute__((address_space(3))) void*)&Bs[ldsbase], 16, 0, 0);
        }
        __syncthreads();
        bf16x8 af[4], bfr[4];
#pragma unroll
        for (int i = 0; i < 4; i++)
            af[i] = *(const bf16x8*)&As[(wr * 64 + i * 16 + lr) * 32 + q * 8];
#pragma unroll
        for (int j = 0; j < 4; j++)
            bfr[j] = *(const bf16x8*)&Bs[(wc * 64 + j * 16 + lr) * 32 + q * 8];
#pragma unroll
        for (int i = 0; i < 4; i++)
#pragma unroll
            for (int j = 0; j < 4; j++)
                acc[i][j] = __builtin_amdgcn_mfma_f32_16x16x32_bf16(af[i], bfr[j], acc[i][j], 0, 0, 0);
        __syncthreads();
    }

#pragma unroll
    for (int i = 0; i < 4; i++) {
#pragma unroll
        for (int j = 0; j < 4; j++) {
            long col = n0 + wc * 64 + j * 16 + lr;
            float bv = bias ? bias[col] : 0.0f;
#pragma unroll
            for (int r = 0; r < 4; r++) {
                long row = m0 + wr * 64 + i * 16 + q * 4 + r;
                float v = acc[i][j][r] + bv;
                if (relu) v = fmaxf(v, 0.0f);
                if (outF) outF[row * strideF + col] = v;
                if (outB) outB[row * strideB + col] = f2bf(v);
            }
        }
    }
}

// ---------------- pooling (mean/max over words) + cc -> bf16 A3 + f32 evF ----
__global__ __launch_bounds__(256) void pool_cc_kernel(
    const float* __restrict__ C2, const void* __restrict__ tok,
    const int* __restrict__ csi, unsigned short* __restrict__ A3,
    float* __restrict__ evF, const int* __restrict__ flag)
{
    int f = *flag;
    int s = blockIdx.x;
    int b = s / EVI;
    long seq = csi[b];
    for (int c = threadIdx.x; c < DIM; c += 256) {
        float mx = -1e30f, sm = 0.0f;
        const float* col = C2 + (long)s * WORDS * DOUT + c;
        for (int w = 0; w < WORDS; w++) {
            float v = col[(long)w * DOUT];
            sm += v;
            mx = fmaxf(mx, v);
        }
        float mean = sm * (1.0f / WORDS);
        evF[(long)s * (2 * DOUT) + c] = mean;
        evF[(long)s * (2 * DOUT) + DOUT + c] = mx;
        A3[(long)s * KATT + c] = f2bf(ldin(tok, seq * LSEQ * DIM + c, f));
        A3[(long)s * KATT + DIM + c] = f2bf(mean);
        A3[(long)s * KATT + DIM + DOUT + c] = f2bf(mx);
    }
}

// ---------------- p = h @ att_w1 ----------------
__global__ __launch_bounds__(256) void pdot_kernel(
    const float* __restrict__ h, const float* __restrict__ w1, float* __restrict__ p)
{
    int i = blockIdx.x;
    float s = 0.0f;
    for (int k = threadIdx.x; k < DOUT; k += 256) s += h[(long)i * DOUT + k] * w1[k];
    __shared__ float red[256];
    red[threadIdx.x] = s;
    __syncthreads();
    for (int o = 128; o > 0; o >>= 1) {
        if (threadIdx.x < o) red[threadIdx.x] += red[threadIdx.x + o];
        __syncthreads();
    }
    if (threadIdx.x == 0) p[i] = red[0];
}

// ---------------- attention output: sigmoid(p[i]) for all 320 rows ----------
__global__ void att_out_kernel(const float* __restrict__ p, float* __restrict__ out)
{
    int i = blockIdx.x * 256 + threadIdx.x;
    if (i < SEQS) out[BN * NCLS + i] = 1.0f / (1.0f + __expf(-p[i]));
}

// ---------------- softmax over EVI + weighted ev + build A4 (bf16) ----------
__global__ __launch_bounds__(256) void softgraph_kernel(
    const float* __restrict__ p, const float* __restrict__ evF,
    const float* __restrict__ ccls, unsigned short* __restrict__ A4)
{
    int b = blockIdx.x;
    __shared__ float a[EVI];
    if (threadIdx.x == 0) {
        float m = -1e30f;
        for (int e = 0; e < EVI; e++) m = fmaxf(m, p[b * EVI + e]);
        float s = 0.0f, ex[EVI];
        for (int e = 0; e < EVI; e++) { ex[e] = __expf(p[b * EVI + e] - m); s += ex[e]; }
        for (int e = 0; e < EVI; e++) a[e] = ex[e] / s;
    }
    __syncthreads();
    for (int d = threadIdx.x; d < 2 * DOUT; d += 256) {
        float g = 0.0f;
        for (int e = 0; e < EVI; e++)
            g += a[e] * evF[(long)(b * EVI + e) * (2 * DOUT) + d];
        A4[(long)b * KATT + d] = f2bf(g);
    }
    for (int c = threadIdx.x; c < DIM; c += 256)
        A4[(long)b * KATT + 2 * DOUT + c] = f2bf(ccls[(long)b * DIM + c]);
}

// ---------------- final: lin2 + log_softmax ----------------
__global__ __launch_bounds__(256) void final_kernel(
    const float* __restrict__ C4, const float* __restrict__ w2,
    const float* __restrict__ bb, float* __restrict__ out)
{
    int b = blockIdx.x;
    float s0 = 0.0f, s1 = 0.0f, s2 = 0.0f;
    for (int k = threadIdx.x; k < LH; k += 256) {
        float h = C4[(long)b * LH + k];
        s0 += h * w2[k * NCLS + 0];
        s1 += h * w2[k * NCLS + 1];
        s2 += h * w2[k * NCLS + 2];
    }
    __shared__ float r0[256], r1[256], r2[256];
    int t = threadIdx.x;
    r0[t] = s0; r1[t] = s1; r2[t] = s2;
    __syncthreads();
    for (int o = 128; o > 0; o >>= 1) {
        if (t < o) { r0[t] += r0[t + o]; r1[t] += r1[t + o]; r2[t] += r2[t + o]; }
        __syncthreads();
    }
    if (t == 0) {
        float l0 = r0[0] + bb[0], l1 = r1[0] + bb[1], l2 = r2[0] + bb[2];
        float m = fmaxf(l0, fmaxf(l1, l2));
        float lse = logf(__expf(l0 - m) + __expf(l1 - m) + __expf(l2 - m)) + m;
        out[b * NCLS + 0] = l0 - lse;
        out[b * NCLS + 1] = l1 - lse;
        out[b * NCLS + 2] = l2 - lse;
    }
}

extern "C" void kernel_launch(void* const* d_in, const int* in_sizes, int n_in,
                              void* d_out, int out_size, void* d_ws, size_t ws_size,
                              hipStream_t stream)
{
    const void* tok      = d_in[0];
    const void* ccls_r   = d_in[1];
    const void* W_rel1_r = d_in[2];
    const void* W_root1_r= d_in[3];
    const void* b1_r     = d_in[4];
    const void* W_rel2_r = d_in[5];
    const void* W_root2_r= d_in[6];
    const void* b2_r     = d_in[7];
    const void* att_w0_r = d_in[8];
    const void* att_w1_r = d_in[9];
    const void* lin1_w_r = d_in[10];
    const void* lin1_b_r = d_in[11];
    const void* lin2_w_r = d_in[12];
    const void* lin2_b_r = d_in[13];
    const int* widx      = (const int*)d_in[14];
    const int* ei        = (const int*)d_in[15];
    const int* et        = (const int*)d_in[16];
    const int* csi       = (const int*)d_in[17];
    float* out           = (float*)d_out;

    char* ws = (char*)d_ws;
    size_t off = 0;
    auto alloc = [&](size_t bytes) { size_t o = off; off = (off + bytes + 255) & ~(size_t)255; return o; };

    int* flag   = (int*)(ws + alloc(256));
    float* cclsF   = (float*)(ws + alloc((size_t)BN * DIM * 4));
    float* Wrel1F  = (float*)(ws + alloc((size_t)RREL * DIM * DIM * 4));
    float* Wroot1F = (float*)(ws + alloc((size_t)DIM * DIM * 4));
    float* b1F     = (float*)(ws + alloc((size_t)DIM * 4));
    float* Wrel2F  = (float*)(ws + alloc((size_t)RREL * DIM * DOUT * 4));
    float* Wroot2F = (float*)(ws + alloc((size_t)DIM * DOUT * 4));
    float* b2F     = (float*)(ws + alloc((size_t)DOUT * 4));
    float* aw0F    = (float*)(ws + alloc((size_t)KATT * DOUT * 4));
    float* aw1F    = (float*)(ws + alloc((size_t)DOUT * 4));
    float* l1wF    = (float*)(ws + alloc((size_t)KATT * LH * 4));
    float* l1bF    = (float*)(ws + alloc((size_t)LH * 4));
    float* l2wF    = (float*)(ws + alloc((size_t)LH * NCLS * 4));
    float* l2bF    = (float*)(ws + alloc((size_t)NCLS * 4));
    unsigned short* xb  = (unsigned short*)(ws + alloc((size_t)NNODE * DIM * 2));
    unsigned short* A1  = (unsigned short*)(ws + alloc((size_t)NNODE * KBIG * 2));
    unsigned short* X1  = (unsigned short*)(ws + alloc((size_t)NNODE * DOUT * 2));
    unsigned short* Wt1 = (unsigned short*)(ws + alloc((size_t)DIM * KBIG * 2));
    unsigned short* Wt2 = (unsigned short*)(ws + alloc((size_t)DIM * KBIG * 2));
    unsigned short* Wt3 = (unsigned short*)(ws + alloc((size_t)DOUT * KATT * 2));
    unsigned short* Wt4 = (unsigned short*)(ws + alloc((size_t)LH * KATT * 2));
    float* C2           = (float*)(ws + alloc((size_t)NNODE * DOUT * 4));
    unsigned short* A3  = (unsigned short*)(ws + alloc((size_t)384 * KATT * 2));
    float* C3           = (float*)(ws + alloc((size_t)384 * DOUT * 4));
    float* evF          = (float*)(ws + alloc((size_t)SEQS * 2 * DOUT * 4));
    float* pbuf         = (float*)(ws + alloc((size_t)SEQS * 4));
    unsigned short* A4  = (unsigned short*)(ws + alloc((size_t)128 * KATT * 2));
    float* C4           = (float*)(ws + alloc((size_t)128 * LH * 4));
    int* cnt            = (int*)(ws + alloc((size_t)2 * NNODE * RREL * 4));
    int* cursor         = cnt + NNODE * RREL;
    int* offs           = (int*)(ws + alloc((size_t)(NNODE * RREL + 1) * 4));
    int* sorted         = (int*)(ws + alloc((size_t)NEDGE * 4));
    (void)ws_size; (void)in_sizes; (void)n_in; (void)out_size;

    // dtype detect + canonicalize (flag=0 path verified by R3)
    detect_kernel<<<1, 64, 0, stream>>>(W_rel1_r, flag);
    auto conv = [&](const void* src, float* dst, long n) {
        int grid = (int)min((n + 255) / 256, (long)2048);
        convert_kernel<<<grid, 256, 0, stream>>>(src, dst, n, flag);
    };
    conv(ccls_r,   cclsF,   (long)BN * DIM);
    conv(W_rel1_r, Wrel1F,  (long)RREL * DIM * DIM);
    conv(W_root1_r,Wroot1F, (long)DIM * DIM);
    conv(b1_r,     b1F,     DIM);
    conv(W_rel2_r, Wrel2F,  (long)RREL * DIM * DOUT);
    conv(W_root2_r,Wroot2F, (long)DIM * DOUT);
    conv(b2_r,     b2F,     DOUT);
    conv(att_w0_r, aw0F,    (long)KATT * DOUT);
    conv(att_w1_r, aw1F,    DOUT);
    conv(lin1_w_r, l1wF,    (long)KATT * LH);
    conv(lin1_b_r, l1bF,    LH);
    conv(lin2_w_r, l2wF,    (long)LH * NCLS);
    conv(lin2_b_r, l2bF,    NCLS);

    // edge prep
    hipMemsetAsync(cnt, 0, (size_t)2 * NNODE * RREL * 4, stream);
    count_kernel<<<NEDGE / 256, 256, 0, stream>>>(ei, et, cnt);
    scan_kernel<<<1, 1024, 0, stream>>>(cnt, offs, NNODE * RREL);
    fill_kernel<<<NEDGE / 256, 256, 0, stream>>>(ei, et, offs, cursor, sorted);

    // token gather
    gather_mean_kernel<<<NNODE, 256, 0, stream>>>(tok, widx, xb, flag);

    // weight transposes (f32 -> bf16, B^T layout)
    transpose_cast_kernel<<<dim3(96, 24), 256, 0, stream>>>(Wrel1F, DIM, Wt1, KBIG, 0);
    transpose_cast_kernel<<<dim3(24, 24), 256, 0, stream>>>(Wroot1F, DIM, Wt1, KBIG, 4 * DIM);
    transpose_cast_kernel<<<dim3(96, 24), 256, 0, stream>>>(Wrel2F, DOUT, Wt2, KBIG, 0);
    transpose_cast_kernel<<<dim3(24, 24), 256, 0, stream>>>(Wroot2F, DOUT, Wt2, KBIG, 4 * DIM);
    transpose_cast_kernel<<<dim3(72, 24), 256, 0, stream>>>(aw0F, DOUT, Wt3, KATT, 0);
    transpose_cast_kernel<<<dim3(72, 32), 256, 0, stream>>>(l1wF, LH, Wt4, KATT, 0);

    // layer 1: A1 = [agg_r(xb) | xb];  X1 = relu(A1 @ W1)
    aggregate_kernel<<<NNODE, 256, 0, stream>>>(xb, DIM, offs, sorted, A1, 1);
    gemm_bt_kernel<<<dim3(NNODE / 128, DIM / 128), 256, 0, stream>>>(
        A1, Wt1, KBIG, b1F, 1, nullptr, 0, X1, DOUT);

    // layer 2: A1 = [agg_r(X1) | X1];  C2 = relu(A1 @ W2)  (f32)
    aggregate_kernel<<<NNODE, 256, 0, stream>>>(X1, DOUT, offs, sorted, A1, 1);
    gemm_bt_kernel<<<dim3(NNODE / 128, DOUT / 128), 256, 0, stream>>>(
        A1, Wt2, KBIG, b2F, 1, C2, DOUT, nullptr, 0);

    // pooling + attention MLP (MFMA)
    pool_cc_kernel<<<SEQS, 256, 0, stream>>>(C2, tok, csi, A3, evF, flag);
    gemm_bt_kernel<<<dim3(3, DOUT / 128), 256, 0, stream>>>(
        A3, Wt3, KATT, nullptr, 1, C3, DOUT, nullptr, 0);
    pdot_kernel<<<SEQS, 256, 0, stream>>>(C3, aw1F, pbuf);
    att_out_kernel<<<(SEQS + 255) / 256, 256, 0, stream>>>(pbuf, out);
    softgraph_kernel<<<BN, 256, 0, stream>>>(pbuf, evF, cclsF, A4);

    // classifier head (MFMA)
    gemm_bt_kernel<<<dim3(1, LH / 128), 256, 0, stream>>>(
        A4, Wt4, KATT, l1bF, 1, C4, LH, nullptr, 0);
    final_kernel<<<BN, 256, 0, stream>>>(C4, l2wF, l2bF, out);
}